// Round 10
// baseline (16681.520 us; speedup 1.0000x reference)
//
#include <hip/hip_runtime.h>
#include <cstdint>
#include <cstddef>

#define T_ 4
#define B_ 8
#define C_ 512
#define N_ 1024
#define SPK_ELEMS (T_*B_*C_*N_)   // 16,777,216 elements (u8)

__device__ const int d_HG[4] = {2, 3, 5, 8};

// Static BSS scratch (no d_ws dependency). Deterministic: every byte read is
// written earlier in the same launch (or never touched and stays zero).
__device__ uint8_t g_spk[3ull * SPK_ELEMS];               // q,k,v spikes (u8)
__device__ float   g_kvw[(size_t)T_ * B_ * 8 * 64 * 64];  // k^T v per (t,b,head)
__device__ uint8_t g_sspk[SPK_ELEMS];                     // attn-lif spikes (u8)

__device__ inline int get_h(const int* gran) {
    int g = *gran;
    if (g < 0 || g > 3) g = 2;
    return d_HG[g];
}

// ---------------------------------------------------------------------------
// K1 (tiled + double-buffered, f32, np-exact): QKV GEMM + BN + LIF -> spikes.
// PRECISION CONTRACT (proven rounds 7-9): per output, ascending-c chain of
// acc = __fadd_rn(acc, __fmul_rn(w, x)); BN/LIF per-op _rn; no FMA.
// Double-buffering changes STAGING ONLY; the per-output accumulation chain
// (kc ascending, kk 0..15 ascending) is identical to round 9's (bit-exact).
// One barrier per kc-step; global loads for step i+1 issued before compute
// of step i (latency hidden under 2048 VALU instrs).
// grid (16 n-tiles, 24 = p*8 + o-tile, 8 b), block 256, 4 blocks/CU.
// ---------------------------------------------------------------------------
__global__ __launch_bounds__(256, 4) void k1t(
    const float* __restrict__ x,
    const float* __restrict__ wq, const float* __restrict__ wk, const float* __restrict__ wv,
    const float* __restrict__ qg, const float* __restrict__ qb, const float* __restrict__ qm, const float* __restrict__ qv,
    const float* __restrict__ kg, const float* __restrict__ kb, const float* __restrict__ km, const float* __restrict__ kvv,
    const float* __restrict__ vg, const float* __restrict__ vb, const float* __restrict__ vm, const float* __restrict__ vvv)
{
    __shared__ float Ws[2][16][64];         // 8 KB
    __shared__ float Xs[2][T_][16][64];     // 32 KB   (total 40 KB)

    const int tid = threadIdx.x;
    const int bx = blockIdx.x;           // n tile
    const int by = blockIdx.y;           // p*8 + o-tile
    const int bz = blockIdx.z;           // b
    const int p  = by >> 3;
    const int ob0 = (by & 7) * 64;

    const float* W  = (p==0) ? wq : (p==1) ? wk : wv;
    const float* gg = (p==0) ? qg : (p==1) ? kg : vg;
    const float* bb = (p==0) ? qb : (p==1) ? kb : vb;
    const float* mm = (p==0) ? qm : (p==1) ? km : vm;
    const float* va = (p==0) ? qv : (p==1) ? kvv : vvv;

    const int r = tid >> 4;              // 0..15 (o sub-row / kk stage row)
    const int c = tid & 15;              // 0..15 (n sub-col, x4)
    const int n0 = bx * 64;
    const int oo = tid & 63, kq = tid >> 6;

    const float* Wld = W + (size_t)(ob0 + oo) * C_ + kq * 4;          // + kc
    const float* Xld = x + ((size_t)(bz*C_) + r) * N_ + n0 + c*4;     // + t*B*C*N + kc*N

    float acc[T_][4][4];
    #pragma unroll
    for (int t = 0; t < T_; ++t)
        #pragma unroll
        for (int i = 0; i < 4; ++i)
            #pragma unroll
            for (int j = 0; j < 4; ++j) acc[t][i][j] = 0.f;

    // prologue: stage kc=0 into buffer 0
    {
        float4 w4 = *(const float4*)(Wld + 0);
        Ws[0][kq*4+0][oo] = w4.x;
        Ws[0][kq*4+1][oo] = w4.y;
        Ws[0][kq*4+2][oo] = w4.z;
        Ws[0][kq*4+3][oo] = w4.w;
        #pragma unroll
        for (int t = 0; t < T_; ++t)
            *(float4*)&Xs[0][t][r][c*4] =
                *(const float4*)(Xld + (size_t)t*B_*C_*N_);
    }
    __syncthreads();

    const int NKC = C_ / 16;             // 32 steps
    for (int it = 0; it < NKC; ++it) {
        const int cur = it & 1;

        // issue next tile's global loads (latency hidden under compute)
        float4 wn; float4 xn[T_];
        const bool more = (it + 1 < NKC);
        if (more) {
            int kc = (it + 1) * 16;
            wn = *(const float4*)(Wld + kc);
            #pragma unroll
            for (int t = 0; t < T_; ++t)
                xn[t] = *(const float4*)(Xld + (size_t)t*B_*C_*N_ + (size_t)kc*N_);
        }

        // compute from buf[cur]  (c = it*16 + kk, kk ascending -> np chain)
        #pragma unroll
        for (int kk = 0; kk < 16; ++kk) {
            float av[4];
            *(float4*)av = *(float4*)&Ws[cur][kk][r*4];
            #pragma unroll
            for (int t = 0; t < T_; ++t) {
                float xv[4];
                *(float4*)xv = *(float4*)&Xs[cur][t][kk][c*4];
                #pragma unroll
                for (int i = 0; i < 4; ++i)
                    #pragma unroll
                    for (int j = 0; j < 4; ++j)
                        acc[t][i][j] = __fadd_rn(acc[t][i][j], __fmul_rn(av[i], xv[j]));
            }
        }

        // write next tile into the other buffer (read only after the barrier)
        if (more) {
            const int nxt = cur ^ 1;
            Ws[nxt][kq*4+0][oo] = wn.x;
            Ws[nxt][kq*4+1][oo] = wn.y;
            Ws[nxt][kq*4+2][oo] = wn.z;
            Ws[nxt][kq*4+3][oo] = wn.w;
            #pragma unroll
            for (int t = 0; t < T_; ++t)
                *(float4*)&Xs[nxt][t][r][c*4] = xn[t];
        }
        __syncthreads();
    }

    // epilogue: BN + LIF (v_th = 1.0), f32 _rn ops (np-exact)
    float inv[4], cst[4];
    #pragma unroll
    for (int i = 0; i < 4; ++i) {
        int o = ob0 + r*4 + i;
        float iv = __fdiv_rn(gg[o], __fsqrt_rn(__fadd_rn(va[o], 1e-5f)));
        inv[i] = iv;
        cst[i] = __fsub_rn(bb[o], __fmul_rn(mm[o], iv));
    }
    #pragma unroll
    for (int i = 0; i < 4; ++i) {
        uint8_t sp[T_][4];
        #pragma unroll
        for (int j = 0; j < 4; ++j) {
            float v = 0.f;
            #pragma unroll
            for (int t = 0; t < T_; ++t) {
                float xbn = __fadd_rn(__fmul_rn(acc[t][i][j], inv[i]), cst[i]);
                v = __fadd_rn(v, __fmul_rn(__fsub_rn(xbn, v), 0.5f));
                uint8_t s = (v >= 1.0f) ? (uint8_t)1 : (uint8_t)0;
                sp[t][j] = s;
                if (s) v = 0.f;
            }
        }
        int o = ob0 + r*4 + i;
        #pragma unroll
        for (int t = 0; t < T_; ++t) {
            uchar4 u; u.x = sp[t][0]; u.y = sp[t][1]; u.z = sp[t][2]; u.w = sp[t][3];
            *(uchar4*)(g_spk + (size_t)p * SPK_ELEMS
                       + ((size_t)((t*B_ + bz)*C_) + o) * N_ + n0 + c*4) = u;
        }
    }
}

// ---------------------------------------------------------------------------
// K2a: kv[i][j] = sum_n k[n,i]*v[n,j] per (t,b,head). Exact small integers
// (sums <= 1024 < 2^24) -> bit-exact in f32 in ANY order (FMA fine).
// grid (8 heads, 8 b, 4 t), block 256.
// ---------------------------------------------------------------------------
__global__ __launch_bounds__(256, 1) void k2a_kv(const int* __restrict__ gran)
{
    const int head = blockIdx.x, b = blockIdx.y, t = blockIdx.z;
    if (head >= get_h(gran)) return;

    __shared__ float sk[128][68];
    __shared__ float sv[128][68];

    const int tid = threadIdx.x;
    const uint8_t* kp = g_spk + (size_t)1*SPK_ELEMS + ((size_t)((t*B_+b)*C_) + head*64) * N_;
    const uint8_t* vp = g_spk + (size_t)2*SPK_ELEMS + ((size_t)((t*B_+b)*C_) + head*64) * N_;

    const int i  = tid & 63;
    const int j0 = (tid >> 6) * 16;

    float acc[16];
    #pragma unroll
    for (int j = 0; j < 16; ++j) acc[j] = 0.f;

    const int ri = tid >> 2, seg = tid & 3;

    for (int nc = 0; nc < N_; nc += 128) {
        #pragma unroll
        for (int u = 0; u < 8; ++u) {
            int col = seg*32 + u*4;
            uint32_t wk = *(const uint32_t*)(kp + (size_t)ri*N_ + nc + col);
            uint32_t wv = *(const uint32_t*)(vp + (size_t)ri*N_ + nc + col);
            sk[col+0][ri] = (float)( wk        & 255u);
            sk[col+1][ri] = (float)((wk >>  8) & 255u);
            sk[col+2][ri] = (float)((wk >> 16) & 255u);
            sk[col+3][ri] = (float)((wk >> 24) & 255u);
            sv[col+0][ri] = (float)( wv        & 255u);
            sv[col+1][ri] = (float)((wv >>  8) & 255u);
            sv[col+2][ri] = (float)((wv >> 16) & 255u);
            sv[col+3][ri] = (float)((wv >> 24) & 255u);
        }
        __syncthreads();
        #pragma unroll 4
        for (int nn = 0; nn < 128; ++nn) {
            float ki = sk[nn][i];
            float4 v0 = *(float4*)&sv[nn][j0 + 0];
            float4 v1 = *(float4*)&sv[nn][j0 + 4];
            float4 v2 = *(float4*)&sv[nn][j0 + 8];
            float4 v3 = *(float4*)&sv[nn][j0 + 12];
            acc[0]  += ki * v0.x; acc[1]  += ki * v0.y; acc[2]  += ki * v0.z; acc[3]  += ki * v0.w;
            acc[4]  += ki * v1.x; acc[5]  += ki * v1.y; acc[6]  += ki * v1.z; acc[7]  += ki * v1.w;
            acc[8]  += ki * v2.x; acc[9]  += ki * v2.y; acc[10] += ki * v2.z; acc[11] += ki * v2.w;
            acc[12] += ki * v3.x; acc[13] += ki * v3.y; acc[14] += ki * v3.z; acc[15] += ki * v3.w;
        }
        __syncthreads();
    }

    float* out = g_kvw + ((size_t)((t*B_+b)*8 + head)) * 4096 + i*64 + j0;
    #pragma unroll
    for (int q4 = 0; q4 < 4; ++q4) {
        float4 o4; o4.x = acc[q4*4+0]; o4.y = acc[q4*4+1]; o4.z = acc[q4*4+2]; o4.w = acc[q4*4+3];
        *(float4*)(out + q4*4) = o4;
    }
}

// ---------------------------------------------------------------------------
// K2b: y[n][d] = 0.25*sum_e q[n,e]*kv[e][d] (exact integers), then attn-LIF
// (v_th=0.5). All dyadic rationals < 22 significant bits -> f32 EXACT.
// grid (4 n-chunks, 8 heads, 8 b), block 256 (thread = one n).
// ---------------------------------------------------------------------------
__global__ __launch_bounds__(256, 1) void k2b_attn(const int* __restrict__ gran)
{
    const int bx = blockIdx.x, head = blockIdx.y, b = blockIdx.z;
    if (head >= get_h(gran)) return;

    __shared__ float    kvs[64*64];
    __shared__ uint32_t qsu[64*64];

    const int tid = threadIdx.x;
    const int n0 = bx * 256;

    float vmem[64];
    #pragma unroll
    for (int j = 0; j < 64; ++j) vmem[j] = 0.f;

    for (int t = 0; t < T_; ++t) {
        const float*   kvp = g_kvw + ((size_t)((t*B_+b)*8 + head)) * 4096;
        const uint8_t* qp  = g_spk + ((size_t)((t*B_+b)*C_) + head*64) * N_ + n0;

        #pragma unroll
        for (int cc = 0; cc < 4; ++cc)
            *(float4*)&kvs[cc*1024 + tid*4] = *(const float4*)(kvp + cc*1024 + tid*4);
        #pragma unroll
        for (int u = 0; u < 16; ++u) {
            int flat = u * 256 + tid;          // 0..4095
            int ch   = flat >> 6;              // channel e
            int w    = flat & 63;              // 4-position group
            qsu[flat] = *(const uint32_t*)(qp + (size_t)ch * N_ + w * 4);
        }
        __syncthreads();

        float acc[64];
        #pragma unroll
        for (int j = 0; j < 64; ++j) acc[j] = 0.f;

        #pragma unroll 4
        for (int e = 0; e < 64; ++e) {
            uint32_t w = qsu[e*64 + (tid >> 2)];
            float qf = (float)((w >> ((tid & 3) * 8)) & 255u);
            #pragma unroll
            for (int j4 = 0; j4 < 16; ++j4) {
                float4 kv4 = *(float4*)&kvs[e*64 + j4*4];
                acc[j4*4+0] += qf * kv4.x;
                acc[j4*4+1] += qf * kv4.y;
                acc[j4*4+2] += qf * kv4.z;
                acc[j4*4+3] += qf * kv4.w;
            }
        }
        __syncthreads();

        uint8_t* sp = g_sspk + ((size_t)((t*B_+b)*C_) + head*64) * N_ + n0 + tid;
        #pragma unroll
        for (int j = 0; j < 64; ++j) {
            float y = __fmul_rn(acc[j], 0.25f);                  // exact
            float v = vmem[j];
            v = __fadd_rn(v, __fmul_rn(__fsub_rn(y, v), 0.5f));  // exact dyadic
            uint8_t s = (v >= 0.5f) ? (uint8_t)1 : (uint8_t)0;
            vmem[j] = s ? 0.f : v;
            sp[(size_t)j * N_] = s;
        }
    }
}

// ---------------------------------------------------------------------------
// K4 (tiled + double-buffered, f32, np-exact): proj GEMM over K=h*64 binary
// channels + p_b + BN + LIF -> out (f32 spikes). Same contract as K1.
// grid (16 n-tiles, 8 o-tiles, 8 b), block 256, 4 blocks/CU.
// ---------------------------------------------------------------------------
__global__ __launch_bounds__(256, 4) void k4t(
    const float* __restrict__ pw, const float* __restrict__ pbias,
    const float* __restrict__ pg, const float* __restrict__ pb2,
    const float* __restrict__ pm, const float* __restrict__ pv,
    const int* __restrict__ gran, float* __restrict__ out)
{
    __shared__ float Ws[2][16][64];
    __shared__ float Ss[2][T_][16][64];

    const int tid = threadIdx.x;
    const int bx = blockIdx.x, by = blockIdx.y, bz = blockIdx.z;
    const int K = get_h(gran) * 64;

    const int r = tid >> 4, c = tid & 15;
    const int n0 = bx * 64, o0 = by * 64;
    const int oo = tid & 63, kq = tid >> 6;

    const float* Wld = pw + (size_t)(o0 + oo) * C_ + kq * 4;
    const uint8_t* Sld = g_sspk + ((size_t)(bz*C_) + r) * N_ + n0 + c*4;

    float acc[T_][4][4];
    #pragma unroll
    for (int t = 0; t < T_; ++t)
        #pragma unroll
        for (int i = 0; i < 4; ++i)
            #pragma unroll
            for (int j = 0; j < 4; ++j) acc[t][i][j] = 0.f;

    {
        float4 w4 = *(const float4*)(Wld + 0);
        Ws[0][kq*4+0][oo] = w4.x;
        Ws[0][kq*4+1][oo] = w4.y;
        Ws[0][kq*4+2][oo] = w4.z;
        Ws[0][kq*4+3][oo] = w4.w;
        #pragma unroll
        for (int t = 0; t < T_; ++t) {
            uchar4 s4 = *(const uchar4*)(Sld + (size_t)t*B_*C_*N_);
            float4 f; f.x = (float)s4.x; f.y = (float)s4.y; f.z = (float)s4.z; f.w = (float)s4.w;
            *(float4*)&Ss[0][t][r][c*4] = f;
        }
    }
    __syncthreads();

    const int NKC = K / 16;
    for (int it = 0; it < NKC; ++it) {
        const int cur = it & 1;

        float4 wn; uchar4 sn[T_];
        const bool more = (it + 1 < NKC);
        if (more) {
            int kc = (it + 1) * 16;
            wn = *(const float4*)(Wld + kc);
            #pragma unroll
            for (int t = 0; t < T_; ++t)
                sn[t] = *(const uchar4*)(Sld + (size_t)t*B_*C_*N_ + (size_t)kc*N_);
        }

        #pragma unroll
        for (int kk = 0; kk < 16; ++kk) {
            float av[4];
            *(float4*)av = *(float4*)&Ws[cur][kk][r*4];
            #pragma unroll
            for (int t = 0; t < T_; ++t) {
                float xv[4];
                *(float4*)xv = *(float4*)&Ss[cur][t][kk][c*4];
                #pragma unroll
                for (int i = 0; i < 4; ++i)
                    #pragma unroll
                    for (int j = 0; j < 4; ++j)
                        acc[t][i][j] = __fadd_rn(acc[t][i][j], __fmul_rn(av[i], xv[j]));
            }
        }

        if (more) {
            const int nxt = cur ^ 1;
            Ws[nxt][kq*4+0][oo] = wn.x;
            Ws[nxt][kq*4+1][oo] = wn.y;
            Ws[nxt][kq*4+2][oo] = wn.z;
            Ws[nxt][kq*4+3][oo] = wn.w;
            #pragma unroll
            for (int t = 0; t < T_; ++t) {
                float4 f; f.x = (float)sn[t].x; f.y = (float)sn[t].y;
                f.z = (float)sn[t].z; f.w = (float)sn[t].w;
                *(float4*)&Ss[nxt][t][r][c*4] = f;
            }
        }
        __syncthreads();
    }

    float inv[4], cst[4], pbv[4];
    #pragma unroll
    for (int i = 0; i < 4; ++i) {
        int o = o0 + r*4 + i;
        float iv = __fdiv_rn(pg[o], __fsqrt_rn(__fadd_rn(pv[o], 1e-5f)));
        inv[i] = iv;
        cst[i] = __fsub_rn(pb2[o], __fmul_rn(pm[o], iv));
        pbv[i] = pbias[o];
    }
    #pragma unroll
    for (int i = 0; i < 4; ++i) {
        float ov[T_][4];
        #pragma unroll
        for (int j = 0; j < 4; ++j) {
            float v = 0.f;
            #pragma unroll
            for (int t = 0; t < T_; ++t) {
                float val = __fadd_rn(acc[t][i][j], pbv[i]);
                float xbn = __fadd_rn(__fmul_rn(val, inv[i]), cst[i]);
                v = __fadd_rn(v, __fmul_rn(__fsub_rn(xbn, v), 0.5f));
                int s = (v >= 1.0f);
                ov[t][j] = s ? 1.0f : 0.0f;
                if (s) v = 0.f;
            }
        }
        int o = o0 + r*4 + i;
        #pragma unroll
        for (int t = 0; t < T_; ++t) {
            float4 f; f.x = ov[t][0]; f.y = ov[t][1]; f.z = ov[t][2]; f.w = ov[t][3];
            *(float4*)(out + ((size_t)((t*B_+bz)*C_) + o) * N_ + n0 + c*4) = f;
        }
    }
}

// ---------------------------------------------------------------------------
extern "C" void kernel_launch(void* const* d_in, const int* in_sizes, int n_in,
                              void* d_out, int out_size, void* d_ws, size_t ws_size,
                              hipStream_t stream)
{
    const float* x    = (const float*)d_in[0];
    const int*   gran = (const int*)  d_in[1];
    const float* qw = (const float*)d_in[2];
    const float* qg = (const float*)d_in[3];
    const float* qb = (const float*)d_in[4];
    const float* qm = (const float*)d_in[5];
    const float* qv = (const float*)d_in[6];
    const float* kw = (const float*)d_in[7];
    const float* kg = (const float*)d_in[8];
    const float* kb = (const float*)d_in[9];
    const float* km = (const float*)d_in[10];
    const float* kv = (const float*)d_in[11];
    const float* vw = (const float*)d_in[12];
    const float* vg = (const float*)d_in[13];
    const float* vb = (const float*)d_in[14];
    const float* vm = (const float*)d_in[15];
    const float* vv = (const float*)d_in[16];
    const float* pw = (const float*)d_in[17];
    const float* pbias = (const float*)d_in[18];
    const float* pg = (const float*)d_in[19];
    const float* pb = (const float*)d_in[20];
    const float* pm = (const float*)d_in[21];
    const float* pv = (const float*)d_in[22];
    float* outp = (float*)d_out;   // reference output dtype = float32

    k1t<<<dim3(16, 24, 8), 256, 0, stream>>>(
        x, qw, kw, vw, qg, qb, qm, qv, kg, kb, km, kv, vg, vb, vm, vv);
    k2a_kv<<<dim3(8, 8, 4), 256, 0, stream>>>(gran);
    k2b_attn<<<dim3(4, 8, 8), 256, 0, stream>>>(gran);
    k4t<<<dim3(16, 8, 8), 256, 0, stream>>>(
        pw, pbias, pg, pb, pm, pv, gran, outp);
}

// Round 11
// 6506.213 us; speedup vs baseline: 2.5639x; 2.5639x over previous
//
#include <hip/hip_runtime.h>
#include <cstdint>
#include <cstddef>

#define T_ 4
#define B_ 8
#define C_ 512
#define N_ 1024
#define SPK_ELEMS (T_*B_*C_*N_)   // 16,777,216 elements (u8)

__device__ const int d_HG[4] = {2, 3, 5, 8};

// Static BSS scratch (no d_ws dependency). Deterministic: every byte read is
// written earlier in the same launch (or never touched and stays zero).
__device__ uint8_t g_spk[3ull * SPK_ELEMS];               // q,k,v spikes (u8)
__device__ float   g_kvw[(size_t)T_ * B_ * 8 * 64 * 64];  // k^T v per (t,b,head)
__device__ uint8_t g_sspk[SPK_ELEMS];                     // attn-lif spikes (u8)

__device__ inline int get_h(const int* gran) {
    int g = *gran;
    if (g < 0 || g > 3) g = 2;
    return d_HG[g];
}

// ---------------------------------------------------------------------------
// K1 (tiled + double-buffered, f32, np-exact): QKV GEMM + BN + LIF -> spikes.
// PRECISION CONTRACT (proven rounds 7-10): per output, ascending-c chain of
// acc = __fadd_rn(acc, __fmul_rn(w, x)); BN/LIF per-op _rn; no FMA.
// launch_bounds(256,2): round 10 showed (256,4) caps VGPRs -> acc spills to
// scratch (31.7 GB writes, 22x slowdown). (256,2) gave clean 72-VGPR code in
// round 9; double-buffer needs ~100 VGPRs, well under the 256 cap.
// grid (16 n-tiles, 24 = p*8 + o-tile, 8 b), block 256.
// ---------------------------------------------------------------------------
__global__ __launch_bounds__(256, 2) void k1t(
    const float* __restrict__ x,
    const float* __restrict__ wq, const float* __restrict__ wk, const float* __restrict__ wv,
    const float* __restrict__ qg, const float* __restrict__ qb, const float* __restrict__ qm, const float* __restrict__ qv,
    const float* __restrict__ kg, const float* __restrict__ kb, const float* __restrict__ km, const float* __restrict__ kvv,
    const float* __restrict__ vg, const float* __restrict__ vb, const float* __restrict__ vm, const float* __restrict__ vvv)
{
    __shared__ float Ws[2][16][64];         // 8 KB
    __shared__ float Xs[2][T_][16][64];     // 32 KB   (total 40 KB)

    const int tid = threadIdx.x;
    const int bx = blockIdx.x;           // n tile
    const int by = blockIdx.y;           // p*8 + o-tile
    const int bz = blockIdx.z;           // b
    const int p  = by >> 3;
    const int ob0 = (by & 7) * 64;

    const float* W  = (p==0) ? wq : (p==1) ? wk : wv;
    const float* gg = (p==0) ? qg : (p==1) ? kg : vg;
    const float* bb = (p==0) ? qb : (p==1) ? kb : vb;
    const float* mm = (p==0) ? qm : (p==1) ? km : vm;
    const float* va = (p==0) ? qv : (p==1) ? kvv : vvv;

    const int r = tid >> 4;              // 0..15 (o sub-row / stage row)
    const int c = tid & 15;              // 0..15 (n sub-col, x4)
    const int n0 = bx * 64;
    const int oo = tid & 63, kq = tid >> 6;

    const float* Wld = W + (size_t)(ob0 + oo) * C_ + kq * 4;          // + kc
    const float* Xld = x + ((size_t)(bz*C_) + r) * N_ + n0 + c*4;     // + t*B*C*N + kc*N

    float acc[T_][4][4];
    #pragma unroll
    for (int t = 0; t < T_; ++t)
        #pragma unroll
        for (int i = 0; i < 4; ++i)
            #pragma unroll
            for (int j = 0; j < 4; ++j) acc[t][i][j] = 0.f;

    // prologue: stage kc=0 into buffer 0
    {
        float4 w4 = *(const float4*)(Wld + 0);
        Ws[0][kq*4+0][oo] = w4.x;
        Ws[0][kq*4+1][oo] = w4.y;
        Ws[0][kq*4+2][oo] = w4.z;
        Ws[0][kq*4+3][oo] = w4.w;
        #pragma unroll
        for (int t = 0; t < T_; ++t)
            *(float4*)&Xs[0][t][r][c*4] =
                *(const float4*)(Xld + (size_t)t*B_*C_*N_);
    }
    __syncthreads();

    const int NKC = C_ / 16;             // 32 steps
    for (int it = 0; it < NKC; ++it) {
        const int cur = it & 1;

        // issue next tile's global loads (latency hidden under compute)
        float4 wn; float4 xn[T_];
        const bool more = (it + 1 < NKC);
        if (more) {
            int kc = (it + 1) * 16;
            wn = *(const float4*)(Wld + kc);
            #pragma unroll
            for (int t = 0; t < T_; ++t)
                xn[t] = *(const float4*)(Xld + (size_t)t*B_*C_*N_ + (size_t)kc*N_);
        }

        // compute from buf[cur]  (c = it*16 + kk, kk ascending -> np chain)
        #pragma unroll
        for (int kk = 0; kk < 16; ++kk) {
            float av[4];
            *(float4*)av = *(float4*)&Ws[cur][kk][r*4];
            #pragma unroll
            for (int t = 0; t < T_; ++t) {
                float xv[4];
                *(float4*)xv = *(float4*)&Xs[cur][t][kk][c*4];
                #pragma unroll
                for (int i = 0; i < 4; ++i)
                    #pragma unroll
                    for (int j = 0; j < 4; ++j)
                        acc[t][i][j] = __fadd_rn(acc[t][i][j], __fmul_rn(av[i], xv[j]));
            }
        }

        // write next tile into the other buffer (read only after the barrier)
        if (more) {
            const int nxt = cur ^ 1;
            Ws[nxt][kq*4+0][oo] = wn.x;
            Ws[nxt][kq*4+1][oo] = wn.y;
            Ws[nxt][kq*4+2][oo] = wn.z;
            Ws[nxt][kq*4+3][oo] = wn.w;
            #pragma unroll
            for (int t = 0; t < T_; ++t)
                *(float4*)&Xs[nxt][t][r][c*4] = xn[t];
        }
        __syncthreads();
    }

    // epilogue: BN + LIF (v_th = 1.0), f32 _rn ops (np-exact)
    float inv[4], cst[4];
    #pragma unroll
    for (int i = 0; i < 4; ++i) {
        int o = ob0 + r*4 + i;
        float iv = __fdiv_rn(gg[o], __fsqrt_rn(__fadd_rn(va[o], 1e-5f)));
        inv[i] = iv;
        cst[i] = __fsub_rn(bb[o], __fmul_rn(mm[o], iv));
    }
    #pragma unroll
    for (int i = 0; i < 4; ++i) {
        uint8_t sp[T_][4];
        #pragma unroll
        for (int j = 0; j < 4; ++j) {
            float v = 0.f;
            #pragma unroll
            for (int t = 0; t < T_; ++t) {
                float xbn = __fadd_rn(__fmul_rn(acc[t][i][j], inv[i]), cst[i]);
                v = __fadd_rn(v, __fmul_rn(__fsub_rn(xbn, v), 0.5f));
                uint8_t s = (v >= 1.0f) ? (uint8_t)1 : (uint8_t)0;
                sp[t][j] = s;
                if (s) v = 0.f;
            }
        }
        int o = ob0 + r*4 + i;
        #pragma unroll
        for (int t = 0; t < T_; ++t) {
            uchar4 u; u.x = sp[t][0]; u.y = sp[t][1]; u.z = sp[t][2]; u.w = sp[t][3];
            *(uchar4*)(g_spk + (size_t)p * SPK_ELEMS
                       + ((size_t)((t*B_ + bz)*C_) + o) * N_ + n0 + c*4) = u;
        }
    }
}

// ---------------------------------------------------------------------------
// K2a: kv[i][j] = sum_n k[n,i]*v[n,j] per (t,b,head). Exact small integers
// (sums <= 1024 < 2^24) -> bit-exact in f32 in ANY order (FMA fine).
// grid (8 heads, 8 b, 4 t), block 256.
// ---------------------------------------------------------------------------
__global__ __launch_bounds__(256, 1) void k2a_kv(const int* __restrict__ gran)
{
    const int head = blockIdx.x, b = blockIdx.y, t = blockIdx.z;
    if (head >= get_h(gran)) return;

    __shared__ float sk[128][68];
    __shared__ float sv[128][68];

    const int tid = threadIdx.x;
    const uint8_t* kp = g_spk + (size_t)1*SPK_ELEMS + ((size_t)((t*B_+b)*C_) + head*64) * N_;
    const uint8_t* vp = g_spk + (size_t)2*SPK_ELEMS + ((size_t)((t*B_+b)*C_) + head*64) * N_;

    const int i  = tid & 63;
    const int j0 = (tid >> 6) * 16;

    float acc[16];
    #pragma unroll
    for (int j = 0; j < 16; ++j) acc[j] = 0.f;

    const int ri = tid >> 2, seg = tid & 3;

    for (int nc = 0; nc < N_; nc += 128) {
        #pragma unroll
        for (int u = 0; u < 8; ++u) {
            int col = seg*32 + u*4;
            uint32_t wk = *(const uint32_t*)(kp + (size_t)ri*N_ + nc + col);
            uint32_t wv = *(const uint32_t*)(vp + (size_t)ri*N_ + nc + col);
            sk[col+0][ri] = (float)( wk        & 255u);
            sk[col+1][ri] = (float)((wk >>  8) & 255u);
            sk[col+2][ri] = (float)((wk >> 16) & 255u);
            sk[col+3][ri] = (float)((wk >> 24) & 255u);
            sv[col+0][ri] = (float)( wv        & 255u);
            sv[col+1][ri] = (float)((wv >>  8) & 255u);
            sv[col+2][ri] = (float)((wv >> 16) & 255u);
            sv[col+3][ri] = (float)((wv >> 24) & 255u);
        }
        __syncthreads();
        #pragma unroll 4
        for (int nn = 0; nn < 128; ++nn) {
            float ki = sk[nn][i];
            float4 v0 = *(float4*)&sv[nn][j0 + 0];
            float4 v1 = *(float4*)&sv[nn][j0 + 4];
            float4 v2 = *(float4*)&sv[nn][j0 + 8];
            float4 v3 = *(float4*)&sv[nn][j0 + 12];
            acc[0]  += ki * v0.x; acc[1]  += ki * v0.y; acc[2]  += ki * v0.z; acc[3]  += ki * v0.w;
            acc[4]  += ki * v1.x; acc[5]  += ki * v1.y; acc[6]  += ki * v1.z; acc[7]  += ki * v1.w;
            acc[8]  += ki * v2.x; acc[9]  += ki * v2.y; acc[10] += ki * v2.z; acc[11] += ki * v2.w;
            acc[12] += ki * v3.x; acc[13] += ki * v3.y; acc[14] += ki * v3.z; acc[15] += ki * v3.w;
        }
        __syncthreads();
    }

    float* out = g_kvw + ((size_t)((t*B_+b)*8 + head)) * 4096 + i*64 + j0;
    #pragma unroll
    for (int q4 = 0; q4 < 4; ++q4) {
        float4 o4; o4.x = acc[q4*4+0]; o4.y = acc[q4*4+1]; o4.z = acc[q4*4+2]; o4.w = acc[q4*4+3];
        *(float4*)(out + q4*4) = o4;
    }
}

// ---------------------------------------------------------------------------
// K2b: y[n][d] = 0.25*sum_e q[n,e]*kv[e][d] (exact integers), then attn-LIF
// (v_th=0.5). All dyadic rationals < 22 significant bits -> f32 EXACT.
// grid (4 n-chunks, 8 heads, 8 b), block 256 (thread = one n).
// ---------------------------------------------------------------------------
__global__ __launch_bounds__(256, 1) void k2b_attn(const int* __restrict__ gran)
{
    const int bx = blockIdx.x, head = blockIdx.y, b = blockIdx.z;
    if (head >= get_h(gran)) return;

    __shared__ float    kvs[64*64];
    __shared__ uint32_t qsu[64*64];

    const int tid = threadIdx.x;
    const int n0 = bx * 256;

    float vmem[64];
    #pragma unroll
    for (int j = 0; j < 64; ++j) vmem[j] = 0.f;

    for (int t = 0; t < T_; ++t) {
        const float*   kvp = g_kvw + ((size_t)((t*B_+b)*8 + head)) * 4096;
        const uint8_t* qp  = g_spk + ((size_t)((t*B_+b)*C_) + head*64) * N_ + n0;

        #pragma unroll
        for (int cc = 0; cc < 4; ++cc)
            *(float4*)&kvs[cc*1024 + tid*4] = *(const float4*)(kvp + cc*1024 + tid*4);
        #pragma unroll
        for (int u = 0; u < 16; ++u) {
            int flat = u * 256 + tid;          // 0..4095
            int ch   = flat >> 6;              // channel e
            int w    = flat & 63;              // 4-position group
            qsu[flat] = *(const uint32_t*)(qp + (size_t)ch * N_ + w * 4);
        }
        __syncthreads();

        float acc[64];
        #pragma unroll
        for (int j = 0; j < 64; ++j) acc[j] = 0.f;

        #pragma unroll 4
        for (int e = 0; e < 64; ++e) {
            uint32_t w = qsu[e*64 + (tid >> 2)];
            float qf = (float)((w >> ((tid & 3) * 8)) & 255u);
            #pragma unroll
            for (int j4 = 0; j4 < 16; ++j4) {
                float4 kv4 = *(float4*)&kvs[e*64 + j4*4];
                acc[j4*4+0] += qf * kv4.x;
                acc[j4*4+1] += qf * kv4.y;
                acc[j4*4+2] += qf * kv4.z;
                acc[j4*4+3] += qf * kv4.w;
            }
        }
        __syncthreads();

        uint8_t* sp = g_sspk + ((size_t)((t*B_+b)*C_) + head*64) * N_ + n0 + tid;
        #pragma unroll
        for (int j = 0; j < 64; ++j) {
            float y = __fmul_rn(acc[j], 0.25f);                  // exact
            float v = vmem[j];
            v = __fadd_rn(v, __fmul_rn(__fsub_rn(y, v), 0.5f));  // exact dyadic
            uint8_t s = (v >= 0.5f) ? (uint8_t)1 : (uint8_t)0;
            vmem[j] = s ? 0.f : v;
            sp[(size_t)j * N_] = s;
        }
    }
}

// ---------------------------------------------------------------------------
// K4 (tiled + double-buffered, f32, np-exact): proj GEMM over K=h*64 binary
// channels + p_b + BN + LIF -> out (f32 spikes). Same contract as K1.
// grid (16 n-tiles, 8 o-tiles, 8 b), block 256.
// ---------------------------------------------------------------------------
__global__ __launch_bounds__(256, 2) void k4t(
    const float* __restrict__ pw, const float* __restrict__ pbias,
    const float* __restrict__ pg, const float* __restrict__ pb2,
    const float* __restrict__ pm, const float* __restrict__ pv,
    const int* __restrict__ gran, float* __restrict__ out)
{
    __shared__ float Ws[2][16][64];
    __shared__ float Ss[2][T_][16][64];

    const int tid = threadIdx.x;
    const int bx = blockIdx.x, by = blockIdx.y, bz = blockIdx.z;
    const int K = get_h(gran) * 64;

    const int r = tid >> 4, c = tid & 15;
    const int n0 = bx * 64, o0 = by * 64;
    const int oo = tid & 63, kq = tid >> 6;

    const float* Wld = pw + (size_t)(o0 + oo) * C_ + kq * 4;
    const uint8_t* Sld = g_sspk + ((size_t)(bz*C_) + r) * N_ + n0 + c*4;

    float acc[T_][4][4];
    #pragma unroll
    for (int t = 0; t < T_; ++t)
        #pragma unroll
        for (int i = 0; i < 4; ++i)
            #pragma unroll
            for (int j = 0; j < 4; ++j) acc[t][i][j] = 0.f;

    {
        float4 w4 = *(const float4*)(Wld + 0);
        Ws[0][kq*4+0][oo] = w4.x;
        Ws[0][kq*4+1][oo] = w4.y;
        Ws[0][kq*4+2][oo] = w4.z;
        Ws[0][kq*4+3][oo] = w4.w;
        #pragma unroll
        for (int t = 0; t < T_; ++t) {
            uchar4 s4 = *(const uchar4*)(Sld + (size_t)t*B_*C_*N_);
            float4 f; f.x = (float)s4.x; f.y = (float)s4.y; f.z = (float)s4.z; f.w = (float)s4.w;
            *(float4*)&Ss[0][t][r][c*4] = f;
        }
    }
    __syncthreads();

    const int NKC = K / 16;
    for (int it = 0; it < NKC; ++it) {
        const int cur = it & 1;

        float4 wn; uchar4 sn[T_];
        const bool more = (it + 1 < NKC);
        if (more) {
            int kc = (it + 1) * 16;
            wn = *(const float4*)(Wld + kc);
            #pragma unroll
            for (int t = 0; t < T_; ++t)
                sn[t] = *(const uchar4*)(Sld + (size_t)t*B_*C_*N_ + (size_t)kc*N_);
        }

        #pragma unroll
        for (int kk = 0; kk < 16; ++kk) {
            float av[4];
            *(float4*)av = *(float4*)&Ws[cur][kk][r*4];
            #pragma unroll
            for (int t = 0; t < T_; ++t) {
                float xv[4];
                *(float4*)xv = *(float4*)&Ss[cur][t][kk][c*4];
                #pragma unroll
                for (int i = 0; i < 4; ++i)
                    #pragma unroll
                    for (int j = 0; j < 4; ++j)
                        acc[t][i][j] = __fadd_rn(acc[t][i][j], __fmul_rn(av[i], xv[j]));
            }
        }

        if (more) {
            const int nxt = cur ^ 1;
            Ws[nxt][kq*4+0][oo] = wn.x;
            Ws[nxt][kq*4+1][oo] = wn.y;
            Ws[nxt][kq*4+2][oo] = wn.z;
            Ws[nxt][kq*4+3][oo] = wn.w;
            #pragma unroll
            for (int t = 0; t < T_; ++t) {
                float4 f; f.x = (float)sn[t].x; f.y = (float)sn[t].y;
                f.z = (float)sn[t].z; f.w = (float)sn[t].w;
                *(float4*)&Ss[nxt][t][r][c*4] = f;
            }
        }
        __syncthreads();
    }

    float inv[4], cst[4], pbv[4];
    #pragma unroll
    for (int i = 0; i < 4; ++i) {
        int o = o0 + r*4 + i;
        float iv = __fdiv_rn(pg[o], __fsqrt_rn(__fadd_rn(pv[o], 1e-5f)));
        inv[i] = iv;
        cst[i] = __fsub_rn(pb2[o], __fmul_rn(pm[o], iv));
        pbv[i] = pbias[o];
    }
    #pragma unroll
    for (int i = 0; i < 4; ++i) {
        float ov[T_][4];
        #pragma unroll
        for (int j = 0; j < 4; ++j) {
            float v = 0.f;
            #pragma unroll
            for (int t = 0; t < T_; ++t) {
                float val = __fadd_rn(acc[t][i][j], pbv[i]);
                float xbn = __fadd_rn(__fmul_rn(val, inv[i]), cst[i]);
                v = __fadd_rn(v, __fmul_rn(__fsub_rn(xbn, v), 0.5f));
                int s = (v >= 1.0f);
                ov[t][j] = s ? 1.0f : 0.0f;
                if (s) v = 0.f;
            }
        }
        int o = o0 + r*4 + i;
        #pragma unroll
        for (int t = 0; t < T_; ++t) {
            float4 f; f.x = ov[t][0]; f.y = ov[t][1]; f.z = ov[t][2]; f.w = ov[t][3];
            *(float4*)(out + ((size_t)((t*B_+bz)*C_) + o) * N_ + n0 + c*4) = f;
        }
    }
}

// ---------------------------------------------------------------------------
extern "C" void kernel_launch(void* const* d_in, const int* in_sizes, int n_in,
                              void* d_out, int out_size, void* d_ws, size_t ws_size,
                              hipStream_t stream)
{
    const float* x    = (const float*)d_in[0];
    const int*   gran = (const int*)  d_in[1];
    const float* qw = (const float*)d_in[2];
    const float* qg = (const float*)d_in[3];
    const float* qb = (const float*)d_in[4];
    const float* qm = (const float*)d_in[5];
    const float* qv = (const float*)d_in[6];
    const float* kw = (const float*)d_in[7];
    const float* kg = (const float*)d_in[8];
    const float* kb = (const float*)d_in[9];
    const float* km = (const float*)d_in[10];
    const float* kv = (const float*)d_in[11];
    const float* vw = (const float*)d_in[12];
    const float* vg = (const float*)d_in[13];
    const float* vb = (const float*)d_in[14];
    const float* vm = (const float*)d_in[15];
    const float* vv = (const float*)d_in[16];
    const float* pw = (const float*)d_in[17];
    const float* pbias = (const float*)d_in[18];
    const float* pg = (const float*)d_in[19];
    const float* pb = (const float*)d_in[20];
    const float* pm = (const float*)d_in[21];
    const float* pv = (const float*)d_in[22];
    float* outp = (float*)d_out;   // reference output dtype = float32

    k1t<<<dim3(16, 24, 8), 256, 0, stream>>>(
        x, qw, kw, vw, qg, qb, qm, qv, kg, kb, km, kv, vg, vb, vm, vv);
    k2a_kv<<<dim3(8, 8, 4), 256, 0, stream>>>(gran);
    k2b_attn<<<dim3(4, 8, 8), 256, 0, stream>>>(gran);
    k4t<<<dim3(16, 8, 8), 256, 0, stream>>>(
        pw, pbias, pg, pb, pm, pv, gran, outp);
}

// Round 12
// 734.979 us; speedup vs baseline: 22.6966x; 8.8522x over previous
//
#include <hip/hip_runtime.h>
#include <cstdint>
#include <cstddef>

#define T_ 4
#define B_ 8
#define C_ 512
#define N_ 1024
#define SPK_ELEMS (T_*B_*C_*N_)   // 16,777,216 elements (u8)

__device__ const int d_HG[4] = {2, 3, 5, 8};

// Static BSS scratch (no d_ws dependency). Deterministic: every byte read is
// written earlier in the same launch (or never touched and stays zero).
__device__ uint8_t g_spk[3ull * SPK_ELEMS];               // q,k,v spikes (u8)
__device__ float   g_kvw[(size_t)T_ * B_ * 8 * 64 * 64];  // k^T v per (t,b,head)
__device__ uint8_t g_sspk[SPK_ELEMS];                     // attn-lif spikes (u8)

__device__ inline int get_h(const int* gran) {
    int g = *gran;
    if (g < 0 || g > 3) g = 2;
    return d_HG[g];
}

// ---------------------------------------------------------------------------
// K1 (tiled, f32, np-exact — round-9 proven structure + dead-head skip):
// QKV GEMM + BN + LIF(v_th=1) -> spikes.
// PRECISION CONTRACT (proven rounds 7-9): per output, ascending-c chain of
// acc = __fadd_rn(acc, __fmul_rn(w, x)); BN/LIF per-op _rn; no FMA.
// DEAD-WORK SKIP: downstream consumes only heads < h (q via k2b, k/v via k2a,
// all with head<h; sspk heads >= h stay zero from BSS). So output channels
// >= h*64 of ALL THREE branches are never read -> blocks with o-tile >= h
// exit immediately (uniform per block, before any barrier; h from device mem,
// deterministic). At h=5 this skips 3/8 of the dominant kernel.
// grid (16 n-tiles, 24 = p*8 + o-tile, 8 b), block 256, 4x4x4t per thread.
// NOTE: VGPR-staged double-buffering was tried (rounds 10/11) and spills
// (the ~20 prefetch VGPRs cannot stay live across the 256-FMA block).
// ---------------------------------------------------------------------------
__global__ __launch_bounds__(256, 2) void k1t(
    const float* __restrict__ x,
    const float* __restrict__ wq, const float* __restrict__ wk, const float* __restrict__ wv,
    const float* __restrict__ qg, const float* __restrict__ qb, const float* __restrict__ qm, const float* __restrict__ qv,
    const float* __restrict__ kg, const float* __restrict__ kb, const float* __restrict__ km, const float* __restrict__ kvv,
    const float* __restrict__ vg, const float* __restrict__ vb, const float* __restrict__ vm, const float* __restrict__ vvv,
    const int* __restrict__ gran)
{
    __shared__ float Ws[16][64];         // 4 KB
    __shared__ float Xs[T_][16][64];     // 16 KB

    const int by = blockIdx.y;           // p*8 + o-tile
    const int h  = get_h(gran);
    if ((by & 7) >= h) return;           // dead channels: never read downstream

    const int tid = threadIdx.x;
    const int bx = blockIdx.x;           // n tile
    const int bz = blockIdx.z;           // b
    const int p  = by >> 3;
    const int ob0 = (by & 7) * 64;

    const float* W  = (p==0) ? wq : (p==1) ? wk : wv;
    const float* gg = (p==0) ? qg : (p==1) ? kg : vg;
    const float* bb = (p==0) ? qb : (p==1) ? kb : vb;
    const float* mm = (p==0) ? qm : (p==1) ? km : vm;
    const float* va = (p==0) ? qv : (p==1) ? kvv : vvv;

    const int r = tid >> 4;              // 0..15 (o sub-row / stage row)
    const int c = tid & 15;              // 0..15 (n sub-col, x4)
    const int n0 = bx * 64;
    const int oo = tid & 63, kq = tid >> 6;

    float acc[T_][4][4];
    #pragma unroll
    for (int t = 0; t < T_; ++t)
        #pragma unroll
        for (int i = 0; i < 4; ++i)
            #pragma unroll
            for (int j = 0; j < 4; ++j) acc[t][i][j] = 0.f;

    for (int kc = 0; kc < C_; kc += 16) {
        // stage W tile (transposed): Ws[kk][oo] = W[ob0+oo][kc+kk]
        float4 w4 = *(const float4*)(W + (size_t)(ob0 + oo) * C_ + kc + kq * 4);
        Ws[kq*4+0][oo] = w4.x;
        Ws[kq*4+1][oo] = w4.y;
        Ws[kq*4+2][oo] = w4.z;
        Ws[kq*4+3][oo] = w4.w;
        // stage X tiles: Xs[t][kk][nn]
        #pragma unroll
        for (int t = 0; t < T_; ++t) {
            const float* xp = x + ((size_t)((t*B_ + bz)*C_) + kc + r) * N_ + n0 + c*4;
            *(float4*)&Xs[t][r][c*4] = *(const float4*)xp;
        }
        __syncthreads();
        #pragma unroll
        for (int kk = 0; kk < 16; ++kk) {     // c = kc + kk, ascending
            float av[4];
            *(float4*)av = *(float4*)&Ws[kk][r*4];
            #pragma unroll
            for (int t = 0; t < T_; ++t) {
                float xv[4];
                *(float4*)xv = *(float4*)&Xs[t][kk][c*4];
                #pragma unroll
                for (int i = 0; i < 4; ++i)
                    #pragma unroll
                    for (int j = 0; j < 4; ++j)
                        acc[t][i][j] = __fadd_rn(acc[t][i][j], __fmul_rn(av[i], xv[j]));
            }
        }
        __syncthreads();
    }

    // epilogue: BN + LIF (v_th = 1.0), f32 _rn ops (np-exact)
    float inv[4], cst[4];
    #pragma unroll
    for (int i = 0; i < 4; ++i) {
        int o = ob0 + r*4 + i;
        float iv = __fdiv_rn(gg[o], __fsqrt_rn(__fadd_rn(va[o], 1e-5f)));
        inv[i] = iv;
        cst[i] = __fsub_rn(bb[o], __fmul_rn(mm[o], iv));
    }
    #pragma unroll
    for (int i = 0; i < 4; ++i) {
        uint8_t sp[T_][4];
        #pragma unroll
        for (int j = 0; j < 4; ++j) {
            float v = 0.f;
            #pragma unroll
            for (int t = 0; t < T_; ++t) {
                float xbn = __fadd_rn(__fmul_rn(acc[t][i][j], inv[i]), cst[i]);
                v = __fadd_rn(v, __fmul_rn(__fsub_rn(xbn, v), 0.5f));
                uint8_t s = (v >= 1.0f) ? (uint8_t)1 : (uint8_t)0;
                sp[t][j] = s;
                if (s) v = 0.f;
            }
        }
        int o = ob0 + r*4 + i;
        #pragma unroll
        for (int t = 0; t < T_; ++t) {
            uchar4 u; u.x = sp[t][0]; u.y = sp[t][1]; u.z = sp[t][2]; u.w = sp[t][3];
            *(uchar4*)(g_spk + (size_t)p * SPK_ELEMS
                       + ((size_t)((t*B_ + bz)*C_) + o) * N_ + n0 + c*4) = u;
        }
    }
}

// ---------------------------------------------------------------------------
// K2a: kv[i][j] = sum_n k[n,i]*v[n,j] per (t,b,head). Exact small integers
// (sums <= 1024 < 2^24) -> bit-exact in f32 in ANY order (FMA fine).
// grid (8 heads, 8 b, 4 t), block 256.
// ---------------------------------------------------------------------------
__global__ __launch_bounds__(256, 1) void k2a_kv(const int* __restrict__ gran)
{
    const int head = blockIdx.x, b = blockIdx.y, t = blockIdx.z;
    if (head >= get_h(gran)) return;

    __shared__ float sk[128][68];
    __shared__ float sv[128][68];

    const int tid = threadIdx.x;
    const uint8_t* kp = g_spk + (size_t)1*SPK_ELEMS + ((size_t)((t*B_+b)*C_) + head*64) * N_;
    const uint8_t* vp = g_spk + (size_t)2*SPK_ELEMS + ((size_t)((t*B_+b)*C_) + head*64) * N_;

    const int i  = tid & 63;
    const int j0 = (tid >> 6) * 16;

    float acc[16];
    #pragma unroll
    for (int j = 0; j < 16; ++j) acc[j] = 0.f;

    const int ri = tid >> 2, seg = tid & 3;

    for (int nc = 0; nc < N_; nc += 128) {
        #pragma unroll
        for (int u = 0; u < 8; ++u) {
            int col = seg*32 + u*4;
            uint32_t wk = *(const uint32_t*)(kp + (size_t)ri*N_ + nc + col);
            uint32_t wv = *(const uint32_t*)(vp + (size_t)ri*N_ + nc + col);
            sk[col+0][ri] = (float)( wk        & 255u);
            sk[col+1][ri] = (float)((wk >>  8) & 255u);
            sk[col+2][ri] = (float)((wk >> 16) & 255u);
            sk[col+3][ri] = (float)((wk >> 24) & 255u);
            sv[col+0][ri] = (float)( wv        & 255u);
            sv[col+1][ri] = (float)((wv >>  8) & 255u);
            sv[col+2][ri] = (float)((wv >> 16) & 255u);
            sv[col+3][ri] = (float)((wv >> 24) & 255u);
        }
        __syncthreads();
        #pragma unroll 4
        for (int nn = 0; nn < 128; ++nn) {
            float ki = sk[nn][i];
            float4 v0 = *(float4*)&sv[nn][j0 + 0];
            float4 v1 = *(float4*)&sv[nn][j0 + 4];
            float4 v2 = *(float4*)&sv[nn][j0 + 8];
            float4 v3 = *(float4*)&sv[nn][j0 + 12];
            acc[0]  += ki * v0.x; acc[1]  += ki * v0.y; acc[2]  += ki * v0.z; acc[3]  += ki * v0.w;
            acc[4]  += ki * v1.x; acc[5]  += ki * v1.y; acc[6]  += ki * v1.z; acc[7]  += ki * v1.w;
            acc[8]  += ki * v2.x; acc[9]  += ki * v2.y; acc[10] += ki * v2.z; acc[11] += ki * v2.w;
            acc[12] += ki * v3.x; acc[13] += ki * v3.y; acc[14] += ki * v3.z; acc[15] += ki * v3.w;
        }
        __syncthreads();
    }

    float* out = g_kvw + ((size_t)((t*B_+b)*8 + head)) * 4096 + i*64 + j0;
    #pragma unroll
    for (int q4 = 0; q4 < 4; ++q4) {
        float4 o4; o4.x = acc[q4*4+0]; o4.y = acc[q4*4+1]; o4.z = acc[q4*4+2]; o4.w = acc[q4*4+3];
        *(float4*)(out + q4*4) = o4;
    }
}

// ---------------------------------------------------------------------------
// K2b: y[n][d] = 0.25*sum_e q[n,e]*kv[e][d] (exact integers), then attn-LIF
// (v_th=0.5). All dyadic rationals < 22 significant bits -> f32 EXACT.
// grid (4 n-chunks, 8 heads, 8 b), block 256 (thread = one n).
// ---------------------------------------------------------------------------
__global__ __launch_bounds__(256, 1) void k2b_attn(const int* __restrict__ gran)
{
    const int bx = blockIdx.x, head = blockIdx.y, b = blockIdx.z;
    if (head >= get_h(gran)) return;

    __shared__ float    kvs[64*64];
    __shared__ uint32_t qsu[64*64];

    const int tid = threadIdx.x;
    const int n0 = bx * 256;

    float vmem[64];
    #pragma unroll
    for (int j = 0; j < 64; ++j) vmem[j] = 0.f;

    for (int t = 0; t < T_; ++t) {
        const float*   kvp = g_kvw + ((size_t)((t*B_+b)*8 + head)) * 4096;
        const uint8_t* qp  = g_spk + ((size_t)((t*B_+b)*C_) + head*64) * N_ + n0;

        #pragma unroll
        for (int cc = 0; cc < 4; ++cc)
            *(float4*)&kvs[cc*1024 + tid*4] = *(const float4*)(kvp + cc*1024 + tid*4);
        #pragma unroll
        for (int u = 0; u < 16; ++u) {
            int flat = u * 256 + tid;          // 0..4095
            int ch   = flat >> 6;              // channel e
            int w    = flat & 63;              // 4-position group
            qsu[flat] = *(const uint32_t*)(qp + (size_t)ch * N_ + w * 4);
        }
        __syncthreads();

        float acc[64];
        #pragma unroll
        for (int j = 0; j < 64; ++j) acc[j] = 0.f;

        #pragma unroll 4
        for (int e = 0; e < 64; ++e) {
            uint32_t w = qsu[e*64 + (tid >> 2)];
            float qf = (float)((w >> ((tid & 3) * 8)) & 255u);
            #pragma unroll
            for (int j4 = 0; j4 < 16; ++j4) {
                float4 kv4 = *(float4*)&kvs[e*64 + j4*4];
                acc[j4*4+0] += qf * kv4.x;
                acc[j4*4+1] += qf * kv4.y;
                acc[j4*4+2] += qf * kv4.z;
                acc[j4*4+3] += qf * kv4.w;
            }
        }
        __syncthreads();

        uint8_t* sp = g_sspk + ((size_t)((t*B_+b)*C_) + head*64) * N_ + n0 + tid;
        #pragma unroll
        for (int j = 0; j < 64; ++j) {
            float y = __fmul_rn(acc[j], 0.25f);                  // exact
            float v = vmem[j];
            v = __fadd_rn(v, __fmul_rn(__fsub_rn(y, v), 0.5f));  // exact dyadic
            uint8_t s = (v >= 0.5f) ? (uint8_t)1 : (uint8_t)0;
            vmem[j] = s ? 0.f : v;
            sp[(size_t)j * N_] = s;
        }
    }
}

// ---------------------------------------------------------------------------
// K4 (tiled, f32, np-exact — round-9 proven structure): proj GEMM over
// K = h*64 binary channels + p_b + BN + LIF(v_th=1) -> out (f32 spikes).
// grid (16 n-tiles, 8 o-tiles, 8 b), block 256.
// ---------------------------------------------------------------------------
__global__ __launch_bounds__(256, 2) void k4t(
    const float* __restrict__ pw, const float* __restrict__ pbias,
    const float* __restrict__ pg, const float* __restrict__ pb2,
    const float* __restrict__ pm, const float* __restrict__ pv,
    const int* __restrict__ gran, float* __restrict__ out)
{
    __shared__ float Ws[16][64];         // 4 KB
    __shared__ float Ss[T_][16][64];     // 16 KB

    const int tid = threadIdx.x;
    const int bx = blockIdx.x, by = blockIdx.y, bz = blockIdx.z;
    const int K = get_h(gran) * 64;

    const int r = tid >> 4, c = tid & 15;
    const int n0 = bx * 64, o0 = by * 64;
    const int oo = tid & 63, kq = tid >> 6;

    float acc[T_][4][4];
    #pragma unroll
    for (int t = 0; t < T_; ++t)
        #pragma unroll
        for (int i = 0; i < 4; ++i)
            #pragma unroll
            for (int j = 0; j < 4; ++j) acc[t][i][j] = 0.f;

    for (int kc = 0; kc < K; kc += 16) {
        float4 w4 = *(const float4*)(pw + (size_t)(o0 + oo) * C_ + kc + kq*4);
        Ws[kq*4+0][oo] = w4.x;
        Ws[kq*4+1][oo] = w4.y;
        Ws[kq*4+2][oo] = w4.z;
        Ws[kq*4+3][oo] = w4.w;
        #pragma unroll
        for (int t = 0; t < T_; ++t) {
            const uint8_t* sp2 = g_sspk + ((size_t)((t*B_+bz)*C_) + kc + r) * N_ + n0 + c*4;
            uchar4 s4 = *(const uchar4*)sp2;
            float4 f; f.x = (float)s4.x; f.y = (float)s4.y; f.z = (float)s4.z; f.w = (float)s4.w;
            *(float4*)&Ss[t][r][c*4] = f;
        }
        __syncthreads();
        #pragma unroll
        for (int kk = 0; kk < 16; ++kk) {     // c = kc + kk, ascending
            float av[4];
            *(float4*)av = *(float4*)&Ws[kk][r*4];
            #pragma unroll
            for (int t = 0; t < T_; ++t) {
                float xv[4];
                *(float4*)xv = *(float4*)&Ss[t][kk][c*4];
                #pragma unroll
                for (int i = 0; i < 4; ++i)
                    #pragma unroll
                    for (int j = 0; j < 4; ++j)
                        acc[t][i][j] = __fadd_rn(acc[t][i][j], __fmul_rn(av[i], xv[j]));
            }
        }
        __syncthreads();
    }

    float inv[4], cst[4], pbv[4];
    #pragma unroll
    for (int i = 0; i < 4; ++i) {
        int o = o0 + r*4 + i;
        float iv = __fdiv_rn(pg[o], __fsqrt_rn(__fadd_rn(pv[o], 1e-5f)));
        inv[i] = iv;
        cst[i] = __fsub_rn(pb2[o], __fmul_rn(pm[o], iv));
        pbv[i] = pbias[o];
    }
    #pragma unroll
    for (int i = 0; i < 4; ++i) {
        float ov[T_][4];
        #pragma unroll
        for (int j = 0; j < 4; ++j) {
            float v = 0.f;
            #pragma unroll
            for (int t = 0; t < T_; ++t) {
                float val = __fadd_rn(acc[t][i][j], pbv[i]);
                float xbn = __fadd_rn(__fmul_rn(val, inv[i]), cst[i]);
                v = __fadd_rn(v, __fmul_rn(__fsub_rn(xbn, v), 0.5f));
                int s = (v >= 1.0f);
                ov[t][j] = s ? 1.0f : 0.0f;
                if (s) v = 0.f;
            }
        }
        int o = o0 + r*4 + i;
        #pragma unroll
        for (int t = 0; t < T_; ++t) {
            float4 f; f.x = ov[t][0]; f.y = ov[t][1]; f.z = ov[t][2]; f.w = ov[t][3];
            *(float4*)(out + ((size_t)((t*B_+bz)*C_) + o) * N_ + n0 + c*4) = f;
        }
    }
}

// ---------------------------------------------------------------------------
extern "C" void kernel_launch(void* const* d_in, const int* in_sizes, int n_in,
                              void* d_out, int out_size, void* d_ws, size_t ws_size,
                              hipStream_t stream)
{
    const float* x    = (const float*)d_in[0];
    const int*   gran = (const int*)  d_in[1];
    const float* qw = (const float*)d_in[2];
    const float* qg = (const float*)d_in[3];
    const float* qb = (const float*)d_in[4];
    const float* qm = (const float*)d_in[5];
    const float* qv = (const float*)d_in[6];
    const float* kw = (const float*)d_in[7];
    const float* kg = (const float*)d_in[8];
    const float* kb = (const float*)d_in[9];
    const float* km = (const float*)d_in[10];
    const float* kv = (const float*)d_in[11];
    const float* vw = (const float*)d_in[12];
    const float* vg = (const float*)d_in[13];
    const float* vb = (const float*)d_in[14];
    const float* vm = (const float*)d_in[15];
    const float* vv = (const float*)d_in[16];
    const float* pw = (const float*)d_in[17];
    const float* pbias = (const float*)d_in[18];
    const float* pg = (const float*)d_in[19];
    const float* pb = (const float*)d_in[20];
    const float* pm = (const float*)d_in[21];
    const float* pv = (const float*)d_in[22];
    float* outp = (float*)d_out;   // reference output dtype = float32

    k1t<<<dim3(16, 24, 8), 256, 0, stream>>>(
        x, qw, kw, vw, qg, qb, qm, qv, kg, kb, km, kv, vg, vb, vm, vv, gran);
    k2a_kv<<<dim3(8, 8, 4), 256, 0, stream>>>(gran);
    k2b_attn<<<dim3(4, 8, 8), 256, 0, stream>>>(gran);
    k4t<<<dim3(16, 8, 8), 256, 0, stream>>>(
        pw, pbias, pg, pb, pm, pv, gran, outp);
}

// Round 13
// 722.166 us; speedup vs baseline: 23.0993x; 1.0177x over previous
//
#include <hip/hip_runtime.h>
#include <cstdint>
#include <cstddef>

#define T_ 4
#define B_ 8
#define C_ 512
#define N_ 1024
#define SPK_ELEMS (T_*B_*C_*N_)   // 16,777,216 elements (u8)

__device__ const int d_HG[4] = {2, 3, 5, 8};

// Static BSS scratch (no d_ws dependency). Deterministic: every byte read is
// written earlier in the same launch (or never touched and stays zero).
__device__ uint8_t g_spk[3ull * SPK_ELEMS];               // q,k,v spikes (u8)
__device__ float   g_kvw[(size_t)T_ * B_ * 8 * 64 * 64];  // k^T v per (t,b,head)
__device__ uint8_t g_sspk[SPK_ELEMS];                     // attn-lif spikes (u8)

__device__ inline int get_h(const int* gran) {
    int g = *gran;
    if (g < 0 || g > 3) g = 2;
    return d_HG[g];
}

// ---------------------------------------------------------------------------
// K1 (tiled BK=32, f32, np-exact): QKV GEMM + BN + LIF(v_th=1) -> spikes.
// PRECISION CONTRACT (proven rounds 7-12): per output, ascending-c chain of
// acc = __fadd_rn(acc, __fmul_rn(w, x)); BN/LIF per-op _rn; no FMA.
// BK=32 (vs 16): halves barrier pairs, doubles compute per step (~2048 cyc)
// to amortize the stage+drain overhead that left 40% VALU idle at BK=16.
// Staging regs are transient within a step (NOT loop-carried -> no spill;
// loop-carried prefetch spilled in rounds 10/11).
// DEAD-HEAD SKIP (round 12): o-tiles >= h are never read downstream -> exit.
// grid (16 n-tiles, 24 = p*8 + o-tile, 8 b), block 256, 4x4x4t per thread.
// ---------------------------------------------------------------------------
__global__ __launch_bounds__(256, 2) void k1t(
    const float* __restrict__ x,
    const float* __restrict__ wq, const float* __restrict__ wk, const float* __restrict__ wv,
    const float* __restrict__ qg, const float* __restrict__ qb, const float* __restrict__ qm, const float* __restrict__ qv,
    const float* __restrict__ kg, const float* __restrict__ kb, const float* __restrict__ km, const float* __restrict__ kvv,
    const float* __restrict__ vg, const float* __restrict__ vb, const float* __restrict__ vm, const float* __restrict__ vvv,
    const int* __restrict__ gran)
{
    __shared__ float Ws[32][64];         // 8 KB
    __shared__ float Xs[T_][32][64];     // 32 KB   (total 40 KB)

    const int by = blockIdx.y;           // p*8 + o-tile
    const int h  = get_h(gran);
    if ((by & 7) >= h) return;           // dead channels: never read downstream

    const int tid = threadIdx.x;
    const int bx = blockIdx.x;           // n tile
    const int bz = blockIdx.z;           // b
    const int p  = by >> 3;
    const int ob0 = (by & 7) * 64;

    const float* W  = (p==0) ? wq : (p==1) ? wk : wv;
    const float* gg = (p==0) ? qg : (p==1) ? kg : vg;
    const float* bb = (p==0) ? qb : (p==1) ? kb : vb;
    const float* mm = (p==0) ? qm : (p==1) ? km : vm;
    const float* va = (p==0) ? qv : (p==1) ? kvv : vvv;

    const int r = tid >> 4;              // 0..15 (stage row / o sub-row)
    const int c = tid & 15;              // 0..15 (n sub-col, x4)
    const int n0 = bx * 64;
    const int oo = tid & 63, kq = tid >> 6;

    float acc[T_][4][4];
    #pragma unroll
    for (int t = 0; t < T_; ++t)
        #pragma unroll
        for (int i = 0; i < 4; ++i)
            #pragma unroll
            for (int j = 0; j < 4; ++j) acc[t][i][j] = 0.f;

    for (int kc = 0; kc < C_; kc += 32) {
        // stage W tile (transposed): Ws[kk][oo] = W[ob0+oo][kc+kk], kk 0..31
        {
            const float* wrow = W + (size_t)(ob0 + oo) * C_ + kc;
            float4 w4a = *(const float4*)(wrow + kq * 4);
            float4 w4b = *(const float4*)(wrow + 16 + kq * 4);
            Ws[kq*4+0][oo] = w4a.x;
            Ws[kq*4+1][oo] = w4a.y;
            Ws[kq*4+2][oo] = w4a.z;
            Ws[kq*4+3][oo] = w4a.w;
            Ws[16+kq*4+0][oo] = w4b.x;
            Ws[16+kq*4+1][oo] = w4b.y;
            Ws[16+kq*4+2][oo] = w4b.z;
            Ws[16+kq*4+3][oo] = w4b.w;
        }
        // stage X tiles: Xs[t][kk][nn], rows r and r+16
        #pragma unroll
        for (int t = 0; t < T_; ++t) {
            const float* xp = x + ((size_t)((t*B_ + bz)*C_) + kc + r) * N_ + n0 + c*4;
            *(float4*)&Xs[t][r][c*4]      = *(const float4*)xp;
            *(float4*)&Xs[t][r+16][c*4]   = *(const float4*)(xp + (size_t)16 * N_);
        }
        __syncthreads();
        #pragma unroll
        for (int kk = 0; kk < 32; ++kk) {     // c = kc + kk, ascending
            float av[4];
            *(float4*)av = *(float4*)&Ws[kk][r*4];
            #pragma unroll
            for (int t = 0; t < T_; ++t) {
                float xv[4];
                *(float4*)xv = *(float4*)&Xs[t][kk][c*4];
                #pragma unroll
                for (int i = 0; i < 4; ++i)
                    #pragma unroll
                    for (int j = 0; j < 4; ++j)
                        acc[t][i][j] = __fadd_rn(acc[t][i][j], __fmul_rn(av[i], xv[j]));
            }
        }
        __syncthreads();
    }

    // epilogue: BN + LIF (v_th = 1.0), f32 _rn ops (np-exact)
    float inv[4], cst[4];
    #pragma unroll
    for (int i = 0; i < 4; ++i) {
        int o = ob0 + r*4 + i;
        float iv = __fdiv_rn(gg[o], __fsqrt_rn(__fadd_rn(va[o], 1e-5f)));
        inv[i] = iv;
        cst[i] = __fsub_rn(bb[o], __fmul_rn(mm[o], iv));
    }
    #pragma unroll
    for (int i = 0; i < 4; ++i) {
        uint8_t sp[T_][4];
        #pragma unroll
        for (int j = 0; j < 4; ++j) {
            float v = 0.f;
            #pragma unroll
            for (int t = 0; t < T_; ++t) {
                float xbn = __fadd_rn(__fmul_rn(acc[t][i][j], inv[i]), cst[i]);
                v = __fadd_rn(v, __fmul_rn(__fsub_rn(xbn, v), 0.5f));
                uint8_t s = (v >= 1.0f) ? (uint8_t)1 : (uint8_t)0;
                sp[t][j] = s;
                if (s) v = 0.f;
            }
        }
        int o = ob0 + r*4 + i;
        #pragma unroll
        for (int t = 0; t < T_; ++t) {
            uchar4 u; u.x = sp[t][0]; u.y = sp[t][1]; u.z = sp[t][2]; u.w = sp[t][3];
            *(uchar4*)(g_spk + (size_t)p * SPK_ELEMS
                       + ((size_t)((t*B_ + bz)*C_) + o) * N_ + n0 + c*4) = u;
        }
    }
}

// ---------------------------------------------------------------------------
// K2a: kv[i][j] = sum_n k[n,i]*v[n,j] per (t,b,head). Exact small integers
// (sums <= 1024 < 2^24) -> bit-exact in f32 in ANY order (FMA fine).
// grid (8 heads, 8 b, 4 t), block 256.
// ---------------------------------------------------------------------------
__global__ __launch_bounds__(256, 1) void k2a_kv(const int* __restrict__ gran)
{
    const int head = blockIdx.x, b = blockIdx.y, t = blockIdx.z;
    if (head >= get_h(gran)) return;

    __shared__ float sk[128][68];
    __shared__ float sv[128][68];

    const int tid = threadIdx.x;
    const uint8_t* kp = g_spk + (size_t)1*SPK_ELEMS + ((size_t)((t*B_+b)*C_) + head*64) * N_;
    const uint8_t* vp = g_spk + (size_t)2*SPK_ELEMS + ((size_t)((t*B_+b)*C_) + head*64) * N_;

    const int i  = tid & 63;
    const int j0 = (tid >> 6) * 16;

    float acc[16];
    #pragma unroll
    for (int j = 0; j < 16; ++j) acc[j] = 0.f;

    const int ri = tid >> 2, seg = tid & 3;

    for (int nc = 0; nc < N_; nc += 128) {
        #pragma unroll
        for (int u = 0; u < 8; ++u) {
            int col = seg*32 + u*4;
            uint32_t wk = *(const uint32_t*)(kp + (size_t)ri*N_ + nc + col);
            uint32_t wv = *(const uint32_t*)(vp + (size_t)ri*N_ + nc + col);
            sk[col+0][ri] = (float)( wk        & 255u);
            sk[col+1][ri] = (float)((wk >>  8) & 255u);
            sk[col+2][ri] = (float)((wk >> 16) & 255u);
            sk[col+3][ri] = (float)((wk >> 24) & 255u);
            sv[col+0][ri] = (float)( wv        & 255u);
            sv[col+1][ri] = (float)((wv >>  8) & 255u);
            sv[col+2][ri] = (float)((wv >> 16) & 255u);
            sv[col+3][ri] = (float)((wv >> 24) & 255u);
        }
        __syncthreads();
        #pragma unroll 4
        for (int nn = 0; nn < 128; ++nn) {
            float ki = sk[nn][i];
            float4 v0 = *(float4*)&sv[nn][j0 + 0];
            float4 v1 = *(float4*)&sv[nn][j0 + 4];
            float4 v2 = *(float4*)&sv[nn][j0 + 8];
            float4 v3 = *(float4*)&sv[nn][j0 + 12];
            acc[0]  += ki * v0.x; acc[1]  += ki * v0.y; acc[2]  += ki * v0.z; acc[3]  += ki * v0.w;
            acc[4]  += ki * v1.x; acc[5]  += ki * v1.y; acc[6]  += ki * v1.z; acc[7]  += ki * v1.w;
            acc[8]  += ki * v2.x; acc[9]  += ki * v2.y; acc[10] += ki * v2.z; acc[11] += ki * v2.w;
            acc[12] += ki * v3.x; acc[13] += ki * v3.y; acc[14] += ki * v3.z; acc[15] += ki * v3.w;
        }
        __syncthreads();
    }

    float* out = g_kvw + ((size_t)((t*B_+b)*8 + head)) * 4096 + i*64 + j0;
    #pragma unroll
    for (int q4 = 0; q4 < 4; ++q4) {
        float4 o4; o4.x = acc[q4*4+0]; o4.y = acc[q4*4+1]; o4.z = acc[q4*4+2]; o4.w = acc[q4*4+3];
        *(float4*)(out + q4*4) = o4;
    }
}

// ---------------------------------------------------------------------------
// K2b: y[n][d] = 0.25*sum_e q[n,e]*kv[e][d] (exact integers), then attn-LIF
// (v_th=0.5). All dyadic rationals < 22 significant bits -> f32 EXACT.
// grid (4 n-chunks, 8 heads, 8 b), block 256 (thread = one n).
// ---------------------------------------------------------------------------
__global__ __launch_bounds__(256, 1) void k2b_attn(const int* __restrict__ gran)
{
    const int bx = blockIdx.x, head = blockIdx.y, b = blockIdx.z;
    if (head >= get_h(gran)) return;

    __shared__ float    kvs[64*64];
    __shared__ uint32_t qsu[64*64];

    const int tid = threadIdx.x;
    const int n0 = bx * 256;

    float vmem[64];
    #pragma unroll
    for (int j = 0; j < 64; ++j) vmem[j] = 0.f;

    for (int t = 0; t < T_; ++t) {
        const float*   kvp = g_kvw + ((size_t)((t*B_+b)*8 + head)) * 4096;
        const uint8_t* qp  = g_spk + ((size_t)((t*B_+b)*C_) + head*64) * N_ + n0;

        #pragma unroll
        for (int cc = 0; cc < 4; ++cc)
            *(float4*)&kvs[cc*1024 + tid*4] = *(const float4*)(kvp + cc*1024 + tid*4);
        #pragma unroll
        for (int u = 0; u < 16; ++u) {
            int flat = u * 256 + tid;          // 0..4095
            int ch   = flat >> 6;              // channel e
            int w    = flat & 63;              // 4-position group
            qsu[flat] = *(const uint32_t*)(qp + (size_t)ch * N_ + w * 4);
        }
        __syncthreads();

        float acc[64];
        #pragma unroll
        for (int j = 0; j < 64; ++j) acc[j] = 0.f;

        #pragma unroll 4
        for (int e = 0; e < 64; ++e) {
            uint32_t w = qsu[e*64 + (tid >> 2)];
            float qf = (float)((w >> ((tid & 3) * 8)) & 255u);
            #pragma unroll
            for (int j4 = 0; j4 < 16; ++j4) {
                float4 kv4 = *(float4*)&kvs[e*64 + j4*4];
                acc[j4*4+0] += qf * kv4.x;
                acc[j4*4+1] += qf * kv4.y;
                acc[j4*4+2] += qf * kv4.z;
                acc[j4*4+3] += qf * kv4.w;
            }
        }
        __syncthreads();

        uint8_t* sp = g_sspk + ((size_t)((t*B_+b)*C_) + head*64) * N_ + n0 + tid;
        #pragma unroll
        for (int j = 0; j < 64; ++j) {
            float y = __fmul_rn(acc[j], 0.25f);                  // exact
            float v = vmem[j];
            v = __fadd_rn(v, __fmul_rn(__fsub_rn(y, v), 0.5f));  // exact dyadic
            uint8_t s = (v >= 0.5f) ? (uint8_t)1 : (uint8_t)0;
            vmem[j] = s ? 0.f : v;
            sp[(size_t)j * N_] = s;
        }
    }
}

// ---------------------------------------------------------------------------
// K4 (tiled BK=32, f32, np-exact): proj GEMM over K=h*64 binary channels +
// p_b + BN + LIF(v_th=1) -> out (f32 spikes). Same contract as K1.
// grid (16 n-tiles, 8 o-tiles, 8 b), block 256.
// ---------------------------------------------------------------------------
__global__ __launch_bounds__(256, 2) void k4t(
    const float* __restrict__ pw, const float* __restrict__ pbias,
    const float* __restrict__ pg, const float* __restrict__ pb2,
    const float* __restrict__ pm, const float* __restrict__ pv,
    const int* __restrict__ gran, float* __restrict__ out)
{
    __shared__ float Ws[32][64];         // 8 KB
    __shared__ float Ss[T_][32][64];     // 32 KB

    const int tid = threadIdx.x;
    const int bx = blockIdx.x, by = blockIdx.y, bz = blockIdx.z;
    const int K = get_h(gran) * 64;      // h*64, multiple of 64 -> BK=32 divides

    const int r = tid >> 4, c = tid & 15;
    const int n0 = bx * 64, o0 = by * 64;
    const int oo = tid & 63, kq = tid >> 6;

    float acc[T_][4][4];
    #pragma unroll
    for (int t = 0; t < T_; ++t)
        #pragma unroll
        for (int i = 0; i < 4; ++i)
            #pragma unroll
            for (int j = 0; j < 4; ++j) acc[t][i][j] = 0.f;

    for (int kc = 0; kc < K; kc += 32) {
        {
            const float* wrow = pw + (size_t)(o0 + oo) * C_ + kc;
            float4 w4a = *(const float4*)(wrow + kq*4);
            float4 w4b = *(const float4*)(wrow + 16 + kq*4);
            Ws[kq*4+0][oo] = w4a.x;
            Ws[kq*4+1][oo] = w4a.y;
            Ws[kq*4+2][oo] = w4a.z;
            Ws[kq*4+3][oo] = w4a.w;
            Ws[16+kq*4+0][oo] = w4b.x;
            Ws[16+kq*4+1][oo] = w4b.y;
            Ws[16+kq*4+2][oo] = w4b.z;
            Ws[16+kq*4+3][oo] = w4b.w;
        }
        #pragma unroll
        for (int t = 0; t < T_; ++t) {
            const uint8_t* sp2 = g_sspk + ((size_t)((t*B_+bz)*C_) + kc + r) * N_ + n0 + c*4;
            uchar4 s4a = *(const uchar4*)sp2;
            uchar4 s4b = *(const uchar4*)(sp2 + (size_t)16 * N_);
            float4 fa; fa.x = (float)s4a.x; fa.y = (float)s4a.y; fa.z = (float)s4a.z; fa.w = (float)s4a.w;
            float4 fb; fb.x = (float)s4b.x; fb.y = (float)s4b.y; fb.z = (float)s4b.z; fb.w = (float)s4b.w;
            *(float4*)&Ss[t][r][c*4]    = fa;
            *(float4*)&Ss[t][r+16][c*4] = fb;
        }
        __syncthreads();
        #pragma unroll
        for (int kk = 0; kk < 32; ++kk) {     // c = kc + kk, ascending
            float av[4];
            *(float4*)av = *(float4*)&Ws[kk][r*4];
            #pragma unroll
            for (int t = 0; t < T_; ++t) {
                float xv[4];
                *(float4*)xv = *(float4*)&Ss[t][kk][c*4];
                #pragma unroll
                for (int i = 0; i < 4; ++i)
                    #pragma unroll
                    for (int j = 0; j < 4; ++j)
                        acc[t][i][j] = __fadd_rn(acc[t][i][j], __fmul_rn(av[i], xv[j]));
            }
        }
        __syncthreads();
    }

    float inv[4], cst[4], pbv[4];
    #pragma unroll
    for (int i = 0; i < 4; ++i) {
        int o = o0 + r*4 + i;
        float iv = __fdiv_rn(pg[o], __fsqrt_rn(__fadd_rn(pv[o], 1e-5f)));
        inv[i] = iv;
        cst[i] = __fsub_rn(pb2[o], __fmul_rn(pm[o], iv));
        pbv[i] = pbias[o];
    }
    #pragma unroll
    for (int i = 0; i < 4; ++i) {
        float ov[T_][4];
        #pragma unroll
        for (int j = 0; j < 4; ++j) {
            float v = 0.f;
            #pragma unroll
            for (int t = 0; t < T_; ++t) {
                float val = __fadd_rn(acc[t][i][j], pbv[i]);
                float xbn = __fadd_rn(__fmul_rn(val, inv[i]), cst[i]);
                v = __fadd_rn(v, __fmul_rn(__fsub_rn(xbn, v), 0.5f));
                int s = (v >= 1.0f);
                ov[t][j] = s ? 1.0f : 0.0f;
                if (s) v = 0.f;
            }
        }
        int o = o0 + r*4 + i;
        #pragma unroll
        for (int t = 0; t < T_; ++t) {
            float4 f; f.x = ov[t][0]; f.y = ov[t][1]; f.z = ov[t][2]; f.w = ov[t][3];
            *(float4*)(out + ((size_t)((t*B_+bz)*C_) + o) * N_ + n0 + c*4) = f;
        }
    }
}

// ---------------------------------------------------------------------------
extern "C" void kernel_launch(void* const* d_in, const int* in_sizes, int n_in,
                              void* d_out, int out_size, void* d_ws, size_t ws_size,
                              hipStream_t stream)
{
    const float* x    = (const float*)d_in[0];
    const int*   gran = (const int*)  d_in[1];
    const float* qw = (const float*)d_in[2];
    const float* qg = (const float*)d_in[3];
    const float* qb = (const float*)d_in[4];
    const float* qm = (const float*)d_in[5];
    const float* qv = (const float*)d_in[6];
    const float* kw = (const float*)d_in[7];
    const float* kg = (const float*)d_in[8];
    const float* kb = (const float*)d_in[9];
    const float* km = (const float*)d_in[10];
    const float* kv = (const float*)d_in[11];
    const float* vw = (const float*)d_in[12];
    const float* vg = (const float*)d_in[13];
    const float* vb = (const float*)d_in[14];
    const float* vm = (const float*)d_in[15];
    const float* vv = (const float*)d_in[16];
    const float* pw = (const float*)d_in[17];
    const float* pbias = (const float*)d_in[18];
    const float* pg = (const float*)d_in[19];
    const float* pb = (const float*)d_in[20];
    const float* pm = (const float*)d_in[21];
    const float* pv = (const float*)d_in[22];
    float* outp = (float*)d_out;   // reference output dtype = float32

    k1t<<<dim3(16, 24, 8), 256, 0, stream>>>(
        x, qw, kw, vw, qg, qb, qm, qv, kg, kb, km, kv, vg, vb, vm, vv, gran);
    k2a_kv<<<dim3(8, 8, 4), 256, 0, stream>>>(gran);
    k2b_attn<<<dim3(4, 8, 8), 256, 0, stream>>>(gran);
    k4t<<<dim3(16, 8, 8), 256, 0, stream>>>(
        pw, pbias, pg, pb, pm, pv, gran, outp);
}